// Round 4
// baseline (105.008 us; speedup 1.0000x reference)
//
#include <hip/hip_runtime.h>
#include <math.h>

constexpr int Bb = 4, Cc = 64, Hh = 256, Ww = 256;
constexpr int RR = 4;  // output rows per block (strip height)

#define LOG2E 1.44269504088896340736f
#define LN2   0.69314718055994530942f

__device__ __forceinline__ unsigned int fenc(float f) {
  unsigned int u = __float_as_uint(f);
  return (u & 0x80000000u) ? ~u : (u | 0x80000000u);
}
__device__ __forceinline__ float fdec(unsigned int k) {
  return __uint_as_float((k & 0x80000000u) ? (k ^ 0x80000000u) : ~k);
}

// Separable formulation: entropy = ln(s) - ws/s with s = 3x3 box of e^v,
// ws = 3x3 box of v*e^v (shift-invariance makes window-max subtraction
// unnecessary; |v| <= ~6 so e^v is safe in fp32). Zero-padding contributes
// a=1, b=0, which loading v=0 produces automatically.
//
// Grid: B * (H/RR) blocks (256 = 1/CU). Block (64,16): ty = 4 channels,
// thread = 4 cols (float4), strip of RR output rows via 3-slot register ring.
__global__ __launch_bounds__(1024) void entropy_kernel(const float* __restrict__ x,
                                                       float* __restrict__ e,
                                                       unsigned int* __restrict__ stats) {
  const int b = blockIdx.x >> 6;        // / (Hh/RR)
  const int strip = blockIdx.x & 63;
  const int r0 = strip * RR;
  const int tx = threadIdx.x;           // 0..63
  const int ty = threadIdx.y;           // 0..15
  const int w0 = tx * 4;

  const size_t planeStride = (size_t)Hh * Ww;
  const float* xb = x + ((size_t)b * Cc + (size_t)ty * 4) * planeStride + w0;

  float acc[RR][4];
#pragma unroll
  for (int r = 0; r < RR; ++r)
#pragma unroll
    for (int i = 0; i < 4; ++i) acc[r][i] = 0.f;

  for (int cc = 0; cc < 4; ++cc) {
    const float* plane = xb + (size_t)cc * planeStride;
    float ha[3][4], hb[3][4];
#pragma unroll
    for (int j = 0; j < RR + 2; ++j) {
      const int row = r0 - 1 + j;
      float4 v = make_float4(0.f, 0.f, 0.f, 0.f);
      if (row >= 0 && row < Hh)
        v = *reinterpret_cast<const float4*>(plane + (size_t)row * Ww);
      const float* vp = &v.x;
      float a[4], bb[4];
#pragma unroll
      for (int i = 0; i < 4; ++i) {
        float t = __builtin_amdgcn_exp2f(vp[i] * LOG2E);  // e^v
        a[i] = t;
        bb[i] = vp[i] * t;                                 // v * e^v (natural units)
      }
      // Horizontal halo across lanes; image edge pads -> a=1, b=0.
      float la = __shfl_up(a[3], 1, 64);
      float lb = __shfl_up(bb[3], 1, 64);
      float ra = __shfl_down(a[0], 1, 64);
      float rb = __shfl_down(bb[0], 1, 64);
      la = (tx == 0) ? 1.f : la;   lb = (tx == 0) ? 0.f : lb;
      ra = (tx == 63) ? 1.f : ra;  rb = (tx == 63) ? 0.f : rb;
      const int s0 = j % 3;  // compile-time (j unrolled)
      ha[s0][0] = la + a[0] + a[1];
      ha[s0][1] = a[0] + a[1] + a[2];
      ha[s0][2] = a[1] + a[2] + a[3];
      ha[s0][3] = a[2] + a[3] + ra;
      hb[s0][0] = lb + bb[0] + bb[1];
      hb[s0][1] = bb[0] + bb[1] + bb[2];
      hb[s0][2] = bb[1] + bb[2] + bb[3];
      hb[s0][3] = bb[2] + bb[3] + rb;
      if (j >= 2) {
        const int orow = j - 2;
#pragma unroll
        for (int i = 0; i < 4; ++i) {
          float s = ha[0][i] + ha[1][i] + ha[2][i];
          float w = hb[0][i] + hb[1][i] + hb[2][i];
          acc[orow][i] += LN2 * __builtin_amdgcn_logf(s) - w * __builtin_amdgcn_rcpf(s);
        }
      }
    }
  }

  // Reduce the 16 channel groups.
  __shared__ float red[16][RR][4][64];   // 64 KiB
#pragma unroll
  for (int r = 0; r < RR; ++r)
#pragma unroll
    for (int i = 0; i < 4; ++i) red[ty][r][i][tx] = acc[r][i];
  __syncthreads();
  if (ty < RR) {
    const int r = ty;
    float4 o;
    float* op = &o.x;
    float mn = INFINITY, mx = -INFINITY;
#pragma unroll
    for (int i = 0; i < 4; ++i) {
      float v = 0.f;
#pragma unroll
      for (int g = 0; g < 16; ++g) v += red[g][r][i][tx];
      v *= (1.0f / Cc);
      op[i] = v;
      mn = fminf(mn, v);
      mx = fmaxf(mx, v);
    }
    *reinterpret_cast<float4*>(e + (size_t)(b * Hh + r0 + r) * Ww + w0) = o;

#pragma unroll
    for (int off = 32; off > 0; off >>= 1) {
      mn = fminf(mn, __shfl_down(mn, off, 64));
      mx = fmaxf(mx, __shfl_down(mx, off, 64));
    }
    if (tx == 0) {
      atomicMin(&stats[b], fenc(mn));
      atomicMax(&stats[4 + b], fenc(mx));
    }
  }
}

// In-place normalize d_out. 65536 threads, 4 elements each (float4).
__global__ __launch_bounds__(256) void norm_kernel(float* __restrict__ e,
                                                   const unsigned int* __restrict__ stats) {
  const int t = blockIdx.x * 256 + threadIdx.x;           // 0..65535
  const int b = t >> 14;                                  // (t*4) >> 16
  const float mn = fdec(stats[b]);
  const float mx = fdec(stats[4 + b]);
  const float inv = 1.0f / fmaxf(mx - mn, 1e-6f);
  float4 v = reinterpret_cast<float4*>(e)[t];
  v.x = (v.x - mn) * inv;
  v.y = (v.y - mn) * inv;
  v.z = (v.z - mn) * inv;
  v.w = (v.w - mn) * inv;
  reinterpret_cast<float4*>(e)[t] = v;
}

extern "C" void kernel_launch(void* const* d_in, const int* in_sizes, int n_in,
                              void* d_out, int out_size, void* d_ws, size_t ws_size,
                              hipStream_t stream) {
  const float* x = (const float*)d_in[0];
  float* out = (float*)d_out;                 // e, then normalized in place
  unsigned int* stats = (unsigned int*)d_ws;  // 8 uints

  // Init: min keys -> 0xFFFFFFFF, max keys -> 0.
  hipMemsetAsync(stats, 0xFF, 4 * sizeof(unsigned int), stream);
  hipMemsetAsync(stats + 4, 0x00, 4 * sizeof(unsigned int), stream);

  entropy_kernel<<<dim3(Bb * (Hh / RR)), dim3(64, 16), 0, stream>>>(x, out, stats);
  norm_kernel<<<dim3((Bb * Hh * Ww / 4) / 256), dim3(256), 0, stream>>>(out, stats);
}

// Round 5
// 54.462 us; speedup vs baseline: 1.9281x; 1.9281x over previous
//
#include <hip/hip_runtime.h>
#include <math.h>

constexpr int Bb = 4, Cc = 64, Hh = 256, Ww = 256;
constexpr int RR = 4;  // output rows per block (strip height)

#define LOG2E 1.44269504088896340736f
#define LN2   0.69314718055994530942f

__device__ __forceinline__ unsigned int fenc(float f) {
  unsigned int u = __float_as_uint(f);
  return (u & 0x80000000u) ? ~u : (u | 0x80000000u);
}
__device__ __forceinline__ float fdec(unsigned int k) {
  return __uint_as_float((k & 0x80000000u) ? (k ^ 0x80000000u) : ~k);
}

// Separable formulation: entropy = ln(s) - ws/s with s = 3x3 box of e^v,
// ws = 3x3 box of v*e^v (softmax entropy is shift-invariant; |v| small so
// e^v is safe in fp32). Zero-padding contributes a=1, b=0, which loading
// v=0 produces automatically.
//
// Grid: B * (H/RR) = 256 blocks. Block (64,8): ty = 8 channels each,
// thread = 4 cols (float4), strip of RR output rows, 3-slot register ring.
__global__ __launch_bounds__(512) void entropy_kernel(const float* __restrict__ x,
                                                      float* __restrict__ e,
                                                      unsigned int* __restrict__ stats) {
  const int b = blockIdx.x >> 6;        // / (Hh/RR)
  const int strip = blockIdx.x & 63;
  const int r0 = strip * RR;
  const int tx = threadIdx.x;           // 0..63
  const int ty = threadIdx.y;           // 0..7
  const int w0 = tx * 4;

  const size_t planeStride = (size_t)Hh * Ww;
  const float* xb = x + ((size_t)b * Cc + (size_t)ty * 8) * planeStride + w0;

  float acc[RR][4];
#pragma unroll
  for (int r = 0; r < RR; ++r)
#pragma unroll
    for (int i = 0; i < 4; ++i) acc[r][i] = 0.f;

  for (int cc = 0; cc < 8; ++cc) {   // rolled: controls register pressure
    const float* plane = xb + (size_t)cc * planeStride;

    // Preload the 6 strip rows -> 6 outstanding dwordx4 loads.
    float4 v[RR + 2];
#pragma unroll
    for (int j = 0; j < RR + 2; ++j) {
      const int row = r0 - 1 + j;
      if (row >= 0 && row < Hh)
        v[j] = *reinterpret_cast<const float4*>(plane + (size_t)row * Ww);
      else
        v[j] = make_float4(0.f, 0.f, 0.f, 0.f);
    }

    float ha[3][4], hb[3][4];
#pragma unroll
    for (int j = 0; j < RR + 2; ++j) {
      const float* vp = &v[j].x;
      float a[4], bb[4];
#pragma unroll
      for (int i = 0; i < 4; ++i) {
        float t = __builtin_amdgcn_exp2f(vp[i] * LOG2E);  // e^v
        a[i] = t;
        bb[i] = vp[i] * t;                                // v * e^v
      }
      // Horizontal halo across lanes; image edge pads -> a=1, b=0.
      float la = __shfl_up(a[3], 1, 64);
      float lb = __shfl_up(bb[3], 1, 64);
      float ra = __shfl_down(a[0], 1, 64);
      float rb = __shfl_down(bb[0], 1, 64);
      la = (tx == 0) ? 1.f : la;   lb = (tx == 0) ? 0.f : lb;
      ra = (tx == 63) ? 1.f : ra;  rb = (tx == 63) ? 0.f : rb;
      const int s0 = j % 3;  // compile-time (j unrolled)
      ha[s0][0] = la + a[0] + a[1];
      ha[s0][1] = a[0] + a[1] + a[2];
      ha[s0][2] = a[1] + a[2] + a[3];
      ha[s0][3] = a[2] + a[3] + ra;
      hb[s0][0] = lb + bb[0] + bb[1];
      hb[s0][1] = bb[0] + bb[1] + bb[2];
      hb[s0][2] = bb[1] + bb[2] + bb[3];
      hb[s0][3] = bb[2] + bb[3] + rb;
      if (j >= 2) {
        const int orow = j - 2;
#pragma unroll
        for (int i = 0; i < 4; ++i) {
          float s = ha[0][i] + ha[1][i] + ha[2][i];
          float w = hb[0][i] + hb[1][i] + hb[2][i];
          acc[orow][i] += LN2 * __builtin_amdgcn_logf(s) - w * __builtin_amdgcn_rcpf(s);
        }
      }
    }
  }

  // Reduce the 8 channel groups.
  __shared__ float red[8][RR][4][64];   // 32 KiB
#pragma unroll
  for (int r = 0; r < RR; ++r)
#pragma unroll
    for (int i = 0; i < 4; ++i) red[ty][r][i][tx] = acc[r][i];
  __syncthreads();
  if (ty < RR) {
    const int r = ty;
    float4 o;
    float* op = &o.x;
    float mn = INFINITY, mx = -INFINITY;
#pragma unroll
    for (int i = 0; i < 4; ++i) {
      float vsum = 0.f;
#pragma unroll
      for (int g = 0; g < 8; ++g) vsum += red[g][r][i][tx];
      vsum *= (1.0f / Cc);
      op[i] = vsum;
      mn = fminf(mn, vsum);
      mx = fmaxf(mx, vsum);
    }
    *reinterpret_cast<float4*>(e + (size_t)(b * Hh + r0 + r) * Ww + w0) = o;

#pragma unroll
    for (int off = 32; off > 0; off >>= 1) {
      mn = fminf(mn, __shfl_down(mn, off, 64));
      mx = fmaxf(mx, __shfl_down(mx, off, 64));
    }
    if (tx == 0) {
      atomicMin(&stats[b], fenc(mn));
      atomicMax(&stats[4 + b], fenc(mx));
    }
  }
}

// In-place normalize d_out. 65536 threads, 4 elements each (float4).
__global__ __launch_bounds__(256) void norm_kernel(float* __restrict__ e,
                                                   const unsigned int* __restrict__ stats) {
  const int t = blockIdx.x * 256 + threadIdx.x;           // 0..65535
  const int b = t >> 14;                                  // (t*4) >> 16
  const float mn = fdec(stats[b]);
  const float mx = fdec(stats[4 + b]);
  const float inv = 1.0f / fmaxf(mx - mn, 1e-6f);
  float4 v = reinterpret_cast<float4*>(e)[t];
  v.x = (v.x - mn) * inv;
  v.y = (v.y - mn) * inv;
  v.z = (v.z - mn) * inv;
  v.w = (v.w - mn) * inv;
  reinterpret_cast<float4*>(e)[t] = v;
}

extern "C" void kernel_launch(void* const* d_in, const int* in_sizes, int n_in,
                              void* d_out, int out_size, void* d_ws, size_t ws_size,
                              hipStream_t stream) {
  const float* x = (const float*)d_in[0];
  float* out = (float*)d_out;                 // e, then normalized in place
  unsigned int* stats = (unsigned int*)d_ws;  // 8 uints

  // Init: min keys -> 0xFFFFFFFF, max keys -> 0.
  hipMemsetAsync(stats, 0xFF, 4 * sizeof(unsigned int), stream);
  hipMemsetAsync(stats + 4, 0x00, 4 * sizeof(unsigned int), stream);

  entropy_kernel<<<dim3(Bb * (Hh / RR)), dim3(64, 8), 0, stream>>>(x, out, stats);
  norm_kernel<<<dim3((Bb * Hh * Ww / 4) / 256), dim3(256), 0, stream>>>(out, stats);
}